// Round 1
// baseline (851.884 us; speedup 1.0000x reference)
//
#include <hip/hip_runtime.h>
#include <stdint.h>
#include <stddef.h>

#define NN 100000
#define NE 1600000
#define HID 64
#define NODE_F 64
#define EDGE_F 32

// LDS row strides (in bf16 elements), padded to spread banks, 16B-aligned rows
#define A_STR 104   // 96 + 8
#define B_STR 136   // 128 + 8

typedef __attribute__((ext_vector_type(8))) short bf16x8;
typedef __attribute__((ext_vector_type(4))) float f32x4;

__device__ __forceinline__ unsigned short f2bf(float f) {
    uint32_t u = __builtin_bit_cast(uint32_t, f);
    u += 0x7fffu + ((u >> 16) & 1u);
    return (unsigned short)(u >> 16);
}

__device__ __forceinline__ ushort4 f4tobf(float4 v) {
    ushort4 b;
    b.x = f2bf(v.x); b.y = f2bf(v.y); b.z = f2bf(v.z); b.w = f2bf(v.w);
    return b;
}

// ---------------- Edge kernel ----------------
// Per block: 64 edges. edge_in = [node_features[sender](64) | edge_features(32)] (K=96)
// out[e][n] = prelu(sum_k in[e][k] * W[n][k], alpha[n]); also atomicAdd into node_acc[recv].
__global__ __launch_bounds__(256) void edge_kernel(
    const float* __restrict__ nodef,
    const int*   __restrict__ recv,
    const int*   __restrict__ send,
    const float* __restrict__ edgef,
    const float* __restrict__ W,      // [64][96] row-major
    const float* __restrict__ alpha,  // [64]
    float*       __restrict__ edge_out,
    float*       __restrict__ node_acc)
{
    __shared__ unsigned short sA[64 * A_STR];
    __shared__ unsigned short sW[64 * A_STR];

    const int tid = threadIdx.x;
    const int e0  = blockIdx.x * 64;

    // Stage A: node part — 64 edges x 16 float4 = 1024 loads
    #pragma unroll
    for (int rep = 0; rep < 4; ++rep) {
        int i = rep * 256 + tid;        // 0..1023
        int e = i >> 4, q = i & 15;
        int s = send[e0 + e];
        float4 v = *(const float4*)(nodef + (size_t)s * NODE_F + q * 4);
        *(ushort4*)&sA[e * A_STR + q * 4] = f4tobf(v);
    }
    // Stage A: edge-feature part — 64 edges x 8 float4 = 512 loads
    #pragma unroll
    for (int rep = 0; rep < 2; ++rep) {
        int i = rep * 256 + tid;        // 0..511
        int e = i >> 3, q = i & 7;
        float4 v = *(const float4*)(edgef + (size_t)(e0 + e) * EDGE_F + q * 4);
        *(ushort4*)&sA[e * A_STR + NODE_F + q * 4] = f4tobf(v);
    }
    // Stage W: 64 rows x 24 float4 = 1536 loads (L1/L2-cached)
    #pragma unroll
    for (int rep = 0; rep < 6; ++rep) {
        int i = rep * 256 + tid;        // 0..1535
        int n = i / 24, q = i % 24;
        float4 v = *(const float4*)(W + n * 96 + q * 4);
        *(ushort4*)&sW[n * A_STR + q * 4] = f4tobf(v);
    }
    __syncthreads();

    const int lane  = tid & 63;
    const int wv    = tid >> 6;        // 4 waves
    const int m_off = wv * 16;         // each wave: 16 edges
    const int row16 = lane & 15;
    const int quad  = lane >> 4;

    f32x4 acc[4] = {};                 // 4 n-tiles of 16 cols

    #pragma unroll
    for (int ks = 0; ks < 3; ++ks) {   // K = 96 = 3 x 32
        bf16x8 a = *(const bf16x8*)&sA[(m_off + row16) * A_STR + ks * 32 + quad * 8];
        #pragma unroll
        for (int nt = 0; nt < 4; ++nt) {
            bf16x8 b = *(const bf16x8*)&sW[(nt * 16 + row16) * A_STR + ks * 32 + quad * 8];
            acc[nt] = __builtin_amdgcn_mfma_f32_16x16x32_bf16(a, b, acc[nt], 0, 0, 0);
        }
    }

    // Epilogue: C/D layout col = lane&15, row = quad*4 + reg
    const int rbase = e0 + m_off + quad * 4;
    int myr[4];
    #pragma unroll
    for (int r = 0; r < 4; ++r) myr[r] = recv[rbase + r];

    #pragma unroll
    for (int nt = 0; nt < 4; ++nt) {
        int col = nt * 16 + row16;
        float al = alpha[col];
        #pragma unroll
        for (int r = 0; r < 4; ++r) {
            float v = acc[nt][r];
            v = (v >= 0.f) ? v : al * v;
            edge_out[(size_t)(rbase + r) * HID + col] = v;
            atomicAdd(&node_acc[(size_t)myr[r] * HID + col], v);
        }
    }
}

// ---------------- Node kernel ----------------
// node_in = [node_acc(64) | node_features(64)] (K=128); out = prelu(in @ W^T, alpha)
__global__ __launch_bounds__(256) void node_kernel(
    const float* __restrict__ node_acc,
    const float* __restrict__ nodef,
    const float* __restrict__ W,      // [64][128] row-major
    const float* __restrict__ alpha,  // [64]
    float*       __restrict__ node_out)
{
    __shared__ unsigned short sA[64 * B_STR];
    __shared__ unsigned short sW[64 * B_STR];

    const int tid = threadIdx.x;
    const int n0  = blockIdx.x * 64;

    // Stage A: 64 rows x 32 float4 = 2048 loads
    #pragma unroll
    for (int rep = 0; rep < 8; ++rep) {
        int i = rep * 256 + tid;        // 0..2047
        int e = i >> 5, q = i & 31;
        int node = n0 + e;
        if (node >= NN) node = NN - 1;  // clamp (tail block); rows unused on store
        const float* src = (q < 16) ? (node_acc + (size_t)node * HID + q * 4)
                                    : (nodef + (size_t)node * NODE_F + (q - 16) * 4);
        float4 v = *(const float4*)src;
        *(ushort4*)&sA[e * B_STR + q * 4] = f4tobf(v);
    }
    // Stage W: 64 rows x 32 float4
    #pragma unroll
    for (int rep = 0; rep < 8; ++rep) {
        int i = rep * 256 + tid;
        int n = i >> 5, q = i & 31;
        float4 v = *(const float4*)(W + n * 128 + q * 4);
        *(ushort4*)&sW[n * B_STR + q * 4] = f4tobf(v);
    }
    __syncthreads();

    const int lane  = tid & 63;
    const int wv    = tid >> 6;
    const int m_off = wv * 16;
    const int row16 = lane & 15;
    const int quad  = lane >> 4;

    f32x4 acc[4] = {};

    #pragma unroll
    for (int ks = 0; ks < 4; ++ks) {   // K = 128 = 4 x 32
        bf16x8 a = *(const bf16x8*)&sA[(m_off + row16) * B_STR + ks * 32 + quad * 8];
        #pragma unroll
        for (int nt = 0; nt < 4; ++nt) {
            bf16x8 b = *(const bf16x8*)&sW[(nt * 16 + row16) * B_STR + ks * 32 + quad * 8];
            acc[nt] = __builtin_amdgcn_mfma_f32_16x16x32_bf16(a, b, acc[nt], 0, 0, 0);
        }
    }

    const int rbase = n0 + m_off + quad * 4;
    #pragma unroll
    for (int nt = 0; nt < 4; ++nt) {
        int col = nt * 16 + row16;
        float al = alpha[col];
        #pragma unroll
        for (int r = 0; r < 4; ++r) {
            int node = rbase + r;
            if (node < NN) {
                float v = acc[nt][r];
                v = (v >= 0.f) ? v : al * v;
                node_out[(size_t)node * HID + col] = v;
            }
        }
    }
}

extern "C" void kernel_launch(void* const* d_in, const int* in_sizes, int n_in,
                              void* d_out, int out_size, void* d_ws, size_t ws_size,
                              hipStream_t stream) {
    const float* nodef      = (const float*)d_in[0];
    const int*   eidx       = (const int*)d_in[1];   // [2][NE]: row0=recv, row1=send
    const float* edgef      = (const float*)d_in[2];
    const float* W_edge     = (const float*)d_in[3];
    const float* alpha_edge = (const float*)d_in[4];
    const float* W_node     = (const float*)d_in[5];
    const float* alpha_node = (const float*)d_in[6];

    float* out_node = (float*)d_out;                         // [NN][64] first
    float* out_edge = out_node + (size_t)NN * HID;           // [NE][64] second
    float* node_acc = (float*)d_ws;                          // [NN][64] scratch

    hipMemsetAsync(node_acc, 0, (size_t)NN * HID * sizeof(float), stream);

    edge_kernel<<<NE / 64, 256, 0, stream>>>(
        nodef, eidx, eidx + NE, edgef, W_edge, alpha_edge, out_edge, node_acc);

    node_kernel<<<(NN + 63) / 64, 256, 0, stream>>>(
        node_acc, nodef, W_node, alpha_node, out_node);
}